// Round 3
// baseline (910.283 us; speedup 1.0000x reference)
//
#include <hip/hip_runtime.h>
#include <math.h>

#define BB 8
#define VV 32000
#define SS 512
#define NCHUNK 125
#define CHUNK 256               // NCHUNK * CHUNK == VV
#define NCOL (BB * SS)          // 4096
#define NGRAM 4
#define PP (SS - NGRAM)         // 508
#define NREAL (BB * NCHUNK)     // 1000 real blocks

// Kernel A: per-column (b,s) partial stats (max, argmax, sum-exp) over a V-chunk.
// DIAGNOSTIC ROUND: grid is 2*NREAL. Blocks >= NREAL run the identical access
// pattern + instruction mix against 524 MB of poisoned ws ("ballast") and dump
// to a disjoint scratch region. This doubles the dispatch duration so it either
// crosses the rocprof top-5 cutoff (giving us its counters) or its cost is
// readable from delta-total. Real results are unaffected.
__global__ __launch_bounds__(256) void colstats_kernel(const float* __restrict__ pred,
                                                       const float* __restrict__ ballast_src,
                                                       float* __restrict__ pmax,
                                                       float* __restrict__ psum,
                                                       int* __restrict__ pidx,
                                                       float* __restrict__ bmax,
                                                       float* __restrict__ bsum,
                                                       int* __restrict__ bidx) {
    int bid = blockIdx.x;
    const bool is_real = bid < NREAL;
    if (!is_real) bid -= NREAL;
    const float* __restrict__ src = is_real ? pred : ballast_src;
    float* __restrict__ omax = is_real ? pmax : bmax;
    float* __restrict__ osum = is_real ? psum : bsum;
    int*   __restrict__ oidx = is_real ? pidx : bidx;

    const int b   = bid / NCHUNK;
    const int c   = bid - b * NCHUNK;
    const int tid = threadIdx.x;
    const int vo  = tid >> 7;
    const int s   = (tid & 127) << 2;
    const int v0  = c * CHUNK;

    float m0 = -INFINITY, m1 = -INFINITY, m2 = -INFINITY, m3 = -INFINITY;
    float a0 = 0.f, a1 = 0.f, a2 = 0.f, a3 = 0.f;
    int   i0 = 0, i1 = 0, i2 = 0, i3 = 0;

    const float L2E = 1.4426950408889634f;
    const float* ptr = src + ((size_t)(b * VV + v0 + vo)) * SS + s;
    int v = v0 + vo;
#pragma unroll 8
    for (int k = 0; k < CHUNK / 2; ++k) {
        const float4 x = *(const float4*)ptr;
        ptr += 2 * SS;
        a0 += exp2f(x.x * L2E);
        a1 += exp2f(x.y * L2E);
        a2 += exp2f(x.z * L2E);
        a3 += exp2f(x.w * L2E);
        if (x.x > m0) { m0 = x.x; i0 = v; }
        if (x.y > m1) { m1 = x.y; i1 = v; }
        if (x.z > m2) { m2 = x.z; i2 = v; }
        if (x.w > m3) { m3 = x.w; i3 = v; }
        v += 2;
    }

    __shared__ float smax[256][4];
    __shared__ float ssum[256][4];
    __shared__ int   sidx[256][4];
    smax[tid][0] = m0; smax[tid][1] = m1; smax[tid][2] = m2; smax[tid][3] = m3;
    ssum[tid][0] = a0; ssum[tid][1] = a1; ssum[tid][2] = a2; ssum[tid][3] = a3;
    sidx[tid][0] = i0; sidx[tid][1] = i1; sidx[tid][2] = i2; sidx[tid][3] = i3;
    __syncthreads();

    if (tid < 128) {
        const int o = tid + 128;
        float m[4]  = {smax[tid][0], smax[tid][1], smax[tid][2], smax[tid][3]};
        float a[4]  = {ssum[tid][0], ssum[tid][1], ssum[tid][2], ssum[tid][3]};
        int   ix[4] = {sidx[tid][0], sidx[tid][1], sidx[tid][2], sidx[tid][3]};
#pragma unroll
        for (int j = 0; j < 4; ++j) {
            const float om = smax[o][j];
            const int   oi = sidx[o][j];
            a[j] += ssum[o][j];
            if (om > m[j] || (om == m[j] && oi < ix[j])) { m[j] = om; ix[j] = oi; }
        }
        const size_t ob = (size_t)c * NCOL + (size_t)b * SS + (size_t)s;
#pragma unroll
        for (int j = 0; j < 4; ++j) {
            omax[ob + j] = m[j];
            osum[ob + j] = a[j];
            oidx[ob + j] = ix[j];
        }
    }
}

// Kernel B: combine the 125 chunk-partials per column -> token + penalty.
// One thread per column; consecutive threads -> consecutive addresses (coalesced).
__global__ __launch_bounds__(64) void finalize_kernel(const float* __restrict__ pmax,
                                                      const float* __restrict__ psum,
                                                      const int* __restrict__ pidx,
                                                      int* __restrict__ toks,
                                                      float* __restrict__ pen,
                                                      float* __restrict__ out) {
    const int col = blockIdx.x * 64 + threadIdx.x;   // 0..4095
    if (col == 0) out[0] = 0.0f;

    float m = -INFINITY, sum = 0.f;
    int   idx = 0x7fffffff;
#pragma unroll 5
    for (int c = 0; c < NCHUNK; ++c) {
        const int off = c * NCOL + col;
        const float cm = pmax[off];
        const int   ci = pidx[off];
        sum += psum[off];
        if (cm > m || (cm == m && ci < idx)) { m = cm; idx = ci; }
    }
    // log_softmax at argmax: lprob = m - log(sum_exp); |x| small => no overflow
    const float lprob = m - logf(sum);
    const float p = expf(lprob);
    float om1 = 1.0f - p;
    if (om1 < 1e-20f) om1 = 1e-20f;
    pen[col]  = -logf(om1);
    toks[col] = idx;
}

// Kernel C: per-b repeat mask + masked penalty sum, atomicAdd (/B) into out.
__global__ __launch_bounds__(256) void mask_loss_kernel(const int* __restrict__ toks,
                                                        const float* __restrict__ pen,
                                                        float* __restrict__ out) {
    const int b   = blockIdx.x;
    const int tid = threadIdx.x;
    __shared__ int tk[SS];
    __shared__ int rep[SS];
    for (int i = tid; i < SS; i += 256) { tk[i] = toks[b * SS + i]; rep[i] = 0; }
    __syncthreads();

    for (int i = tid; i < PP; i += 256) {
        const int c0 = tk[i], c1 = tk[i + 1], c2 = tk[i + 2], c3 = tk[i + 3];
        int r = 0;
        for (int j = 0; j < i; ++j) {
            if (tk[j] == c0 && tk[j + 1] == c1 && tk[j + 2] == c2 && tk[j + 3] == c3) {
                r = 1; break;
            }
        }
        rep[i] = r;
    }
    __syncthreads();

    float local = 0.f;
    for (int s = tid; s < SS; s += 256) {
        int msk = 0;
#pragma unroll
        for (int k = 0; k < NGRAM; ++k) {
            const int i = s - k;
            if (i >= 0 && i < PP && rep[i]) msk = 1;
        }
        if (msk) local += pen[b * SS + s];
    }

    for (int off = 32; off > 0; off >>= 1) local += __shfl_down(local, off, 64);
    __shared__ float wsum[4];
    const int lane = tid & 63, wid = tid >> 6;
    if (lane == 0) wsum[wid] = local;
    __syncthreads();
    if (tid == 0) {
        float t = wsum[0] + wsum[1] + wsum[2] + wsum[3];
        atomicAdd(out, t * (1.0f / (float)BB));
    }
}

extern "C" void kernel_launch(void* const* d_in, const int* in_sizes, int n_in,
                              void* d_out, int out_size, void* d_ws, size_t ws_size,
                              hipStream_t stream) {
    const float* pred = (const float*)d_in[0];
    float* out = (float*)d_out;
    char* ws = (char*)d_ws;

    const size_t partN = (size_t)NCHUNK * NCOL;          // 512000
    // Real partials + outputs (first ~6.2 MB of ws)
    float* pmax = (float*)ws;
    float* psum = (float*)(ws + partN * 4);
    int*   pidx = (int*)  (ws + partN * 8);
    int*   toks = (int*)  (ws + partN * 12);
    float* pen  = (float*)(ws + partN * 12 + NCOL * 4);
    // Ballast scratch: dump at +16 MB, source = 524 MB of poisoned ws at +512 MB
    char* bdump = ws + (16u << 20);
    float* bmax = (float*)bdump;
    float* bsum = (float*)(bdump + partN * 4);
    int*   bidx = (int*)  (bdump + partN * 8);
    const float* ballast_src = (const float*)(ws + (512u << 20));

    colstats_kernel<<<2 * NREAL, 256, 0, stream>>>(pred, ballast_src, pmax, psum, pidx,
                                                   bmax, bsum, bidx);
    finalize_kernel<<<NCOL / 64, 64, 0, stream>>>(pmax, psum, pidx, toks, pen, out);
    mask_loss_kernel<<<BB, 256, 0, stream>>>(toks, pen, out);
}

// Round 4
// 715.864 us; speedup vs baseline: 1.2716x; 1.2716x over previous
//
#include <hip/hip_runtime.h>
#include <math.h>

#define BB 8
#define VV 32000
#define SS 512
#define NCHUNK 125
#define CHUNK 256               // NCHUNK * CHUNK == VV
#define NCOL (BB * SS)          // 4096
#define NGRAM 4
#define PP (SS - NGRAM)         // 508
#define NREAL (BB * NCHUNK)     // 1000 blocks

typedef float vfloat4 __attribute__((ext_vector_type(4)));

// Kernel A: per-column (b,s) partial stats (max, argmax, sum-exp) over a V-chunk.
// 1000 blocks, 256 threads. Wave reads 1 KB contiguous (float4/lane).
// VALU diet: exp2 via raw v_exp_f32 builtin (libm exp2f expands to a guarded
// multi-instr sequence -> suspected 3.4 TB/s issue-rate cap), nontemporal loads.
__global__ __launch_bounds__(256) void colstats_kernel(const float* __restrict__ pred,
                                                       float* __restrict__ pmax,
                                                       float* __restrict__ psum,
                                                       int* __restrict__ pidx) {
    const int bid = blockIdx.x;
    const int b   = bid / NCHUNK;
    const int c   = bid - b * NCHUNK;
    const int tid = threadIdx.x;
    const int vo  = tid >> 7;
    const int s   = (tid & 127) << 2;
    const int v0  = c * CHUNK;

    float m0 = -INFINITY, m1 = -INFINITY, m2 = -INFINITY, m3 = -INFINITY;
    float a0 = 0.f, a1 = 0.f, a2 = 0.f, a3 = 0.f;
    int   i0 = 0, i1 = 0, i2 = 0, i3 = 0;

    const float L2E = 1.4426950408889634f;
    const vfloat4* ptr = (const vfloat4*)(pred + ((size_t)(b * VV + v0 + vo)) * SS + s);
    int v = v0 + vo;
#pragma unroll 8
    for (int k = 0; k < CHUNK / 2; ++k) {
        const vfloat4 x = __builtin_nontemporal_load(ptr);
        ptr += (2 * SS) / 4;
        a0 += __builtin_amdgcn_exp2f(x.x * L2E);
        a1 += __builtin_amdgcn_exp2f(x.y * L2E);
        a2 += __builtin_amdgcn_exp2f(x.z * L2E);
        a3 += __builtin_amdgcn_exp2f(x.w * L2E);
        if (x.x > m0) { m0 = x.x; i0 = v; }
        if (x.y > m1) { m1 = x.y; i1 = v; }
        if (x.z > m2) { m2 = x.z; i2 = v; }
        if (x.w > m3) { m3 = x.w; i3 = v; }
        v += 2;
    }

    __shared__ float smax[256][4];
    __shared__ float ssum[256][4];
    __shared__ int   sidx[256][4];
    smax[tid][0] = m0; smax[tid][1] = m1; smax[tid][2] = m2; smax[tid][3] = m3;
    ssum[tid][0] = a0; ssum[tid][1] = a1; ssum[tid][2] = a2; ssum[tid][3] = a3;
    sidx[tid][0] = i0; sidx[tid][1] = i1; sidx[tid][2] = i2; sidx[tid][3] = i3;
    __syncthreads();

    if (tid < 128) {
        const int o = tid + 128;
        float m[4]  = {smax[tid][0], smax[tid][1], smax[tid][2], smax[tid][3]};
        float a[4]  = {ssum[tid][0], ssum[tid][1], ssum[tid][2], ssum[tid][3]};
        int   ix[4] = {sidx[tid][0], sidx[tid][1], sidx[tid][2], sidx[tid][3]};
#pragma unroll
        for (int j = 0; j < 4; ++j) {
            const float om = smax[o][j];
            const int   oi = sidx[o][j];
            a[j] += ssum[o][j];
            if (om > m[j] || (om == m[j] && oi < ix[j])) { m[j] = om; ix[j] = oi; }
        }
        const size_t ob = (size_t)c * NCOL + (size_t)b * SS + (size_t)s;
#pragma unroll
        for (int j = 0; j < 4; ++j) {
            pmax[ob + j] = m[j];
            psum[ob + j] = a[j];
            pidx[ob + j] = ix[j];
        }
    }
}

__global__ void zero_kernel(float* out) { out[0] = 0.0f; }

// Kernel B (fused finalize + mask + loss): one block per batch b, 512 threads,
// one column each. Combine the 125 chunk-partials (coalesced: consecutive
// threads -> consecutive addresses), compute token+penalty into LDS, build the
// n-gram repeat mask, reduce masked penalties, atomicAdd(/B).
__global__ __launch_bounds__(512) void finalize_mask_kernel(const float* __restrict__ pmax,
                                                            const float* __restrict__ psum,
                                                            const int* __restrict__ pidx,
                                                            float* __restrict__ out) {
    const int b   = blockIdx.x;
    const int tid = threadIdx.x;          // 0..511 == s
    const int col = b * SS + tid;

    float m = -INFINITY, sum = 0.f;
    int   idx = 0x7fffffff;
#pragma unroll 5
    for (int c = 0; c < NCHUNK; ++c) {
        const int off = c * NCOL + col;
        const float cm = pmax[off];
        const int   ci = pidx[off];
        sum += psum[off];
        if (cm > m || (cm == m && ci < idx)) { m = cm; idx = ci; }
    }
    const float lprob = m - logf(sum);    // log_softmax at argmax
    const float p = expf(lprob);
    float om1 = 1.0f - p;
    if (om1 < 1e-20f) om1 = 1e-20f;

    __shared__ int   tk[SS];
    __shared__ int   rep[SS];
    __shared__ float pn[SS];
    tk[tid]  = idx;
    pn[tid]  = -logf(om1);
    rep[tid] = 0;
    __syncthreads();

    if (tid < PP) {
        const int c0 = tk[tid], c1 = tk[tid + 1], c2 = tk[tid + 2], c3 = tk[tid + 3];
        int r = 0;
        for (int j = 0; j < tid; ++j) {
            if (tk[j] == c0 && tk[j + 1] == c1 && tk[j + 2] == c2 && tk[j + 3] == c3) {
                r = 1; break;
            }
        }
        rep[tid] = r;
    }
    __syncthreads();

    float local = 0.f;
    {
        int msk = 0;
#pragma unroll
        for (int k = 0; k < NGRAM; ++k) {
            const int i = tid - k;
            if (i >= 0 && i < PP && rep[i]) msk = 1;
        }
        if (msk) local += pn[tid];
    }

    for (int off = 32; off > 0; off >>= 1) local += __shfl_down(local, off, 64);
    __shared__ float wsum[8];
    const int lane = tid & 63, wid = tid >> 6;
    if (lane == 0) wsum[wid] = local;
    __syncthreads();
    if (tid == 0) {
        float t = 0.f;
#pragma unroll
        for (int w = 0; w < 8; ++w) t += wsum[w];
        atomicAdd(out, t * (1.0f / (float)BB));
    }
}

extern "C" void kernel_launch(void* const* d_in, const int* in_sizes, int n_in,
                              void* d_out, int out_size, void* d_ws, size_t ws_size,
                              hipStream_t stream) {
    const float* pred = (const float*)d_in[0];
    float* out = (float*)d_out;
    char* ws = (char*)d_ws;

    const size_t partN = (size_t)NCHUNK * NCOL;          // 512000
    float* pmax = (float*)ws;
    float* psum = (float*)(ws + partN * 4);
    int*   pidx = (int*)  (ws + partN * 8);

    colstats_kernel<<<NREAL, 256, 0, stream>>>(pred, pmax, psum, pidx);
    zero_kernel<<<1, 1, 0, stream>>>(out);
    finalize_mask_kernel<<<BB, 512, 0, stream>>>(pmax, psum, pidx, out);
}